// Round 9
// baseline (160.599 us; speedup 1.0000x reference)
//
#include <hip/hip_runtime.h>
#include <hip/hip_bf16.h>

// Sizes (fixed by the reference setup)
constexpr int B  = 128;
constexpr int D  = 1024;
constexpr int NV = 36;
constexpr int NL = 20;
constexpr int BD = B * D;              // 131072
constexpr float EPS = 0.01f;
constexpr int NSLOT = 8;

// Workspace layout (floats)
constexpr long SL  = 524288;                     // [128][4096] slot
constexpr long SLB = 2097152;                    // [512][4096] slot
constexpr long OFF_GPA   = 0;                    // 8 slots (att gate partials)
constexpr long OFF_GPLB  = OFF_GPA + 8 * SL;     // 8 slots (lbase partials)
constexpr long OFF_LBASE = OFF_GPLB + 8 * SL;    // [128][4096] (incl. biases)
constexpr long OFF_GPB   = OFF_LBASE + SL;       // 2 slots [512][4096] (loop gates)
constexpr long OFF_GPC0  = OFF_GPB + 2 * SLB;    // conf slot 0 [512][1024]
constexpr long OFF_GPC1  = OFF_GPC0 + 524288;    // conf slot 1
constexpr long OFF_HATT2 = OFF_GPC1 + 524288;    // h_att [128][1024]
constexpr long OFF_CATT2 = OFF_HATT2 + BD;
constexpr long OFF_HLB   = OFF_CATT2 + BD;       // h_lang batched [512][1024]
constexpr long OFF_CLB   = OFF_HLB + 524288;
constexpr long OFF_VCTXB = OFF_CLB + 524288;     // vctx batched [512][1024]
constexpr long OFF_LCTXB = OFF_VCTXB + 524288;
constexpr long OFF_S2    = OFF_LCTXB + 524288;   // S = sum h_lang [128][1024]
constexpr long OFF_VVB   = OFF_S2 + BD;          // bf16 vval cache
constexpr long OFF_LVB   = OFF_VVB + 2359296;    // bf16 lval cache
constexpr long OFF_VKB   = OFF_LVB + 1310720;    // bf16 vkey cache
constexpr long OFF_LKB   = OFF_VKB + 2359296;    // bf16 lkey cache

typedef float f32x4 __attribute__((ext_vector_type(4)));
typedef short s16x8 __attribute__((ext_vector_type(8)));

__device__ __forceinline__ float sigf(float x) { return 1.f / (1.f + expf(-x)); }

__device__ __forceinline__ short f2bf(float f) {
  __hip_bfloat16 h = __float2bfloat16(f);
  return *reinterpret_cast<short*>(&h);
}
__device__ __forceinline__ float bf2f(short s) {
  unsigned u = ((unsigned)(unsigned short)s) << 16;
  return __uint_as_float(u);
}

__device__ __forceinline__ f32x4 LD4(const float* p) { return *(const f32x4*)p; }
__device__ __forceinline__ void ST4(float* p, f32x4 v) { *(f32x4*)p = v; }

// ---------------------------------------------------------------------------
// MFMA bf16 GEMM body: split-K partials, double-buffered LDS, tile BM=128
// BN=64 BK=64; blockIdx.(x,y,z) = (N-tile, M-tile, K-slot).
// ---------------------------------------------------------------------------
struct GemmArgs {
  const float* A[NSLOT];
  const float* W[NSLOT];
  long wstride[NSLOT];
  int klen;                // K per z (multiple of 64)
};

__device__ __forceinline__ void gemm_body(const GemmArgs& ga, int N,
                                          long pstride,
                                          float* __restrict__ gpart) {
  __shared__ __align__(16) short As[2][128][72];
  __shared__ __align__(16) short Bs[2][64][72];
  const int z = blockIdx.z;
  const float* __restrict__ A = ga.A[z];
  const float* __restrict__ W = ga.W[z];
  const long wstr = ga.wstride[z];
  const int brow = blockIdx.y * 128;
  const int bcol = blockIdx.x * 64;
  float* __restrict__ out = gpart + (long)z * pstride;

  const int tid = threadIdx.x;
  const int wave = tid >> 6, lane = tid & 63;
  const int wr = wave >> 1, wc = wave & 1;
  const int lrow = lane & 15;
  const int lk8  = (lane >> 4) * 8;
  const int sr = tid >> 4;          // 0..15
  const int sc4 = (tid & 15) * 4;   // 0..60

  f32x4 acc[4][2];
#pragma unroll
  for (int m = 0; m < 4; ++m)
#pragma unroll
    for (int n = 0; n < 2; ++n) acc[m][n] = (f32x4){0.f, 0.f, 0.f, 0.f};

  float4 ra[8], rw[4];
#define LOAD_TILE(KT)                                                          \
  {                                                                            \
    const int kb = (KT) * 64;                                                  \
    _Pragma("unroll") for (int i = 0; i < 8; ++i) {                            \
      const int r = sr + i * 16;                                               \
      ra[i] = *(const float4*)(A + (long)(brow + r) * 1024 + kb + sc4);        \
    }                                                                          \
    _Pragma("unroll") for (int i = 0; i < 4; ++i) {                            \
      const int r = sr + i * 16;                                               \
      rw[i] = *(const float4*)(W + (long)(bcol + r) * wstr + kb + sc4);        \
    }                                                                          \
  }
#define WRITE_TILE(BUF)                                                        \
  {                                                                            \
    _Pragma("unroll") for (int i = 0; i < 8; ++i) {                            \
      const int r = sr + i * 16;                                               \
      *(short4*)(&As[BUF][r][sc4]) =                                           \
          short4{f2bf(ra[i].x), f2bf(ra[i].y), f2bf(ra[i].z), f2bf(ra[i].w)};  \
    }                                                                          \
    _Pragma("unroll") for (int i = 0; i < 4; ++i) {                            \
      const int r = sr + i * 16;                                               \
      *(short4*)(&Bs[BUF][r][sc4]) =                                           \
          short4{f2bf(rw[i].x), f2bf(rw[i].y), f2bf(rw[i].z), f2bf(rw[i].w)};  \
    }                                                                          \
  }

  const int ntiles = ga.klen / 64;
  LOAD_TILE(0);
  WRITE_TILE(0);
  __syncthreads();
  for (int kt = 0; kt < ntiles; ++kt) {
    const int cur = kt & 1;
    const bool more = (kt + 1 < ntiles);
    if (more) LOAD_TILE(kt + 1);  // in flight during MFMA phase
#pragma unroll
    for (int kk = 0; kk < 64; kk += 32) {
      s16x8 af[4], bf[2];
#pragma unroll
      for (int m = 0; m < 4; ++m)
        af[m] = *(const s16x8*)(&As[cur][wr * 64 + m * 16 + lrow][kk + lk8]);
#pragma unroll
      for (int n = 0; n < 2; ++n)
        bf[n] = *(const s16x8*)(&Bs[cur][wc * 32 + n * 16 + lrow][kk + lk8]);
#pragma unroll
      for (int m = 0; m < 4; ++m)
#pragma unroll
        for (int n = 0; n < 2; ++n)
          acc[m][n] = __builtin_amdgcn_mfma_f32_16x16x32_bf16(
              af[m], bf[n], acc[m][n], 0, 0, 0);
    }
    if (more) WRITE_TILE(1 - cur);
    __syncthreads();
  }
#undef LOAD_TILE
#undef WRITE_TILE

  // C/D layout: col=lane&15, row=(lane>>4)*4+reg
#pragma unroll
  for (int m = 0; m < 4; ++m) {
#pragma unroll
    for (int n = 0; n < 2; ++n) {
      const int col = bcol + wc * 32 + n * 16 + lrow;
#pragma unroll
      for (int r = 0; r < 4; ++r) {
        const int row = brow + wr * 64 + m * 16 + (lane >> 4) * 4 + r;
        out[(long)row * N + col] = acc[m][n][r];
      }
    }
  }
}

__global__ __launch_bounds__(256, 2) void gemm_mfma(GemmArgs ga, int N,
                                                    long pstride,
                                                    float* __restrict__ gpart) {
  gemm_body(ga, N, pstride, gpart);
}

// ---------------------------------------------------------------------------
// f32 -> bf16 grid-stride converter (device helper for the fused kernel)
// ---------------------------------------------------------------------------
__device__ __forceinline__ void conv_bf16(const float* __restrict__ src,
                                          __hip_bfloat16* __restrict__ dst,
                                          long nelem, int bid, int nb) {
  const long total = nelem >> 2;
  for (long i = (long)bid * 256 + threadIdx.x; i < total; i += (long)nb * 256) {
    f32x4 v = LD4(src + i * 4);
    *(short4*)((short*)dst + i * 4) =
        short4{f2bf(v[0]), f2bf(v[1]), f2bf(v[2]), f2bf(v[3])};
  }
}

// ---------------------------------------------------------------------------
// Fused: att-gate GEMM (z<8) + K/V bf16 prestage (z>=8, 256 blocks).
// Both roles are independent inputs -> safe horizontal fusion.
// ---------------------------------------------------------------------------
__global__ __launch_bounds__(256, 2) void gemmA_prestage(
    GemmArgs ga, int N, long pstride, float* __restrict__ gpart,
    const float* __restrict__ vkey, const float* __restrict__ lkey,
    const float* __restrict__ vval, const float* __restrict__ lval,
    __hip_bfloat16* __restrict__ vkb, __hip_bfloat16* __restrict__ lkb,
    __hip_bfloat16* __restrict__ vvb, __hip_bfloat16* __restrict__ lvb) {
  if (blockIdx.z < 8) {
    gemm_body(ga, N, pstride, gpart);
  } else {
    const int bid = (blockIdx.z - 8) * 64 + blockIdx.x;  // 0..255
    const int nb = 256;
    conv_bf16(vkey, vkb, (long)B * NV * 1024, bid, nb);
    conv_bf16(lkey, lkb, (long)B * NL * 1024, bid, nb);
    conv_bf16(vval, vvb, (long)B * NV * 1024, bid, nb);
    conv_bf16(lval, lvb, (long)B * NL * 1024, bid, nb);
  }
}

// ---------------------------------------------------------------------------
// att LSTM cell: gates = sum of 8 partials + bih + bhh -> h_att, c_att.
// Also writes new_h[0] / new_c[0] sections of d_out directly.
// ---------------------------------------------------------------------------
constexpr long O1 = BD;
constexpr long O2 = O1 + (long)B * NV * D;
constexpr long O3 = O2 + (long)B * NL * D;
constexpr long O4 = O3 + B;
constexpr long O5 = O4 + 2L * BD;
constexpr long O6 = O5 + 2L * BD;
constexpr long O7 = O6 + BD;

__global__ __launch_bounds__(256) void lstm_att(
    const float* __restrict__ gp, const float* __restrict__ bih,
    const float* __restrict__ bhh, const float* __restrict__ c_prev,
    float* __restrict__ h, float* __restrict__ c, float* __restrict__ out) {
  long idx = ((long)blockIdx.x * 256 + threadIdx.x) * 4;
  if (idx >= BD) return;
  int b = (int)(idx >> 10), d = (int)(idx & 1023);
  const long base = (long)b * 4096 + d;
  f32x4 g[4];
#pragma unroll
  for (int gi = 0; gi < 4; ++gi) {
    const long o = base + gi * 1024;
    f32x4 v = LD4(bih + gi * 1024 + d) + LD4(bhh + gi * 1024 + d);
#pragma unroll
    for (int s = 0; s < NSLOT; ++s) v += LD4(gp + s * SL + o);
    g[gi] = v;
  }
  f32x4 cp = LD4(c_prev + idx), cc, hh;
#pragma unroll
  for (int j = 0; j < 4; ++j) {
    float ccj = sigf(g[1][j]) * cp[j] + sigf(g[0][j]) * tanhf(g[2][j]);
    cc[j] = ccj;
    hh[j] = sigf(g[3][j]) * tanhf(ccj);
  }
  ST4(c + idx, cc);
  ST4(h + idx, hh);
  ST4(out + O4 + idx, hh);   // new_h[0] == hA/accum == h_att
  ST4(out + O5 + idx, cc);   // new_c[0] == cA/accum == c_att
}

// ---------------------------------------------------------------------------
// reduce8: lbase = sum of 8 partials + bih + bhh
// ---------------------------------------------------------------------------
__global__ __launch_bounds__(256) void reduce8(
    const float* __restrict__ gp, const float* __restrict__ bih,
    const float* __restrict__ bhh, float* __restrict__ out) {
  long idx = ((long)blockIdx.x * 256 + threadIdx.x) * 4;
  if (idx >= (long)B * 4096) return;
  int col = (int)(idx & 4095);
  f32x4 v = LD4(bih + col) + LD4(bhh + col);
#pragma unroll
  for (int s = 0; s < NSLOT; ++s) v += LD4(gp + s * SL + idx);
  ST4(out + idx, v);
}

// ---------------------------------------------------------------------------
// attn_mega v3: all 4 attention steps per batch element, 1024 threads.
// Keys staged into LDS from the bf16 cache (L3-warm, half bytes). Values
// read bf16 all steps with 4-way accumulator ILP. kvs recurrence in
// registers. Softmax over ORIGINAL keys (slot-uniform update cancels).
// ---------------------------------------------------------------------------
__global__ __launch_bounds__(1024) void attn_mega(
    const float* __restrict__ h_att, const float* __restrict__ kv0,
    const __hip_bfloat16* __restrict__ vkb, const __hip_bfloat16* __restrict__ lkb,
    const __hip_bfloat16* __restrict__ vvb, const __hip_bfloat16* __restrict__ lvb,
    float* __restrict__ vctxB, float* __restrict__ lctxB,
    float* __restrict__ out_kvs) {
  const int b = blockIdx.x, tid = threadIdx.x;   // tid = d column
  __shared__ short K[56][1024];                  // 112 KB bf16 keys
  __shared__ float q[1024];
  __shared__ float wgt[64];
  const int wave = tid >> 6, lane = tid & 63;

  // stage all 56 keys from bf16 cache (s16x8 = 16B per thread-iter)
  for (int i = tid; i < 56 * 128; i += 1024) {
    const int r = i >> 7, c8 = (i & 127) * 8;
    const __hip_bfloat16* kp = (r < NV)
        ? vkb + ((long)b * NV + r) * 1024
        : lkb + ((long)b * NL + (r - NV)) * 1024;
    *(s16x8*)(&K[r][c8]) = *(const s16x8*)(kp + c8);
  }

  const float ha = h_att[(long)b * 1024 + tid];
  float kv = kv0[(long)b * 1024 + tid];

  for (int step = 0; step < 4; ++step) {
    q[tid] = ha + kv;
    __syncthreads();   // orders K staging (iter 0) and q writes before reads
    // logits: 56 keys over 16 waves, pure LDS
    for (int n = wave; n < NV + NL; n += 16) {
      float s = 0.f;
#pragma unroll
      for (int j = 0; j < 2; ++j) {
        const int base = lane * 8 + j * 512;
        s16x8 k8 = *(const s16x8*)(&K[n][base]);
        f32x4 q0 = *(const f32x4*)(&q[base]);
        f32x4 q1 = *(const f32x4*)(&q[base + 4]);
#pragma unroll
        for (int e = 0; e < 4; ++e) {
          s += bf2f(k8[e]) * q0[e];
          s += bf2f(k8[e + 4]) * q1[e];
        }
      }
      for (int m = 32; m >= 1; m >>= 1) s += __shfl_xor(s, m);
      if (lane == 0) wgt[n] = s * (1.0f / 32.0f);
    }
    __syncthreads();
    // softmax (wave0: visual, wave1: language)
    if (wave == 0) {
      float x = (lane < NV) ? wgt[lane] : -1e30f;
      float m = x;
      for (int k = 32; k >= 1; k >>= 1) m = fmaxf(m, __shfl_xor(m, k));
      float e = (lane < NV) ? expf(x - m) : 0.f;
      float ssum = e;
      for (int k = 32; k >= 1; k >>= 1) ssum += __shfl_xor(ssum, k);
      if (lane < NV) wgt[lane] = e / ssum;
    } else if (wave == 1) {
      float x = (lane < NL) ? wgt[NV + lane] : -1e30f;
      float m = x;
      for (int k = 32; k >= 1; k >>= 1) m = fmaxf(m, __shfl_xor(m, k));
      float e = (lane < NL) ? expf(x - m) : 0.f;
      float ssum = e;
      for (int k = 32; k >= 1; k >>= 1) ssum += __shfl_xor(ssum, k);
      if (lane < NL) wgt[NV + lane] = e / ssum;
    }
    __syncthreads();
    // context + kvs update: 1 col/thread, bf16, 4-way accumulator ILP
    const __hip_bfloat16* vb = vvb + (long)b * NV * 1024 + tid;
    float a0 = 0.f, a1 = 0.f, a2 = 0.f, a3 = 0.f;
#pragma unroll
    for (int n = 0; n < NV; n += 4) {
      a0 += __bfloat162float(vb[(long)(n + 0) * 1024]) * wgt[n + 0];
      a1 += __bfloat162float(vb[(long)(n + 1) * 1024]) * wgt[n + 1];
      a2 += __bfloat162float(vb[(long)(n + 2) * 1024]) * wgt[n + 2];
      a3 += __bfloat162float(vb[(long)(n + 3) * 1024]) * wgt[n + 3];
    }
    const float vc = (a0 + a1) + (a2 + a3);
    const __hip_bfloat16* lb = lvb + (long)b * NL * 1024 + tid;
    float c0 = 0.f, c1 = 0.f, c2 = 0.f, c3 = 0.f;
#pragma unroll
    for (int n = 0; n < NL; n += 4) {
      c0 += __bfloat162float(lb[(long)(n + 0) * 1024]) * wgt[NV + n + 0];
      c1 += __bfloat162float(lb[(long)(n + 1) * 1024]) * wgt[NV + n + 1];
      c2 += __bfloat162float(lb[(long)(n + 2) * 1024]) * wgt[NV + n + 2];
      c3 += __bfloat162float(lb[(long)(n + 3) * 1024]) * wgt[NV + n + 3];
    }
    const float lc = (c0 + c1) + (c2 + c3);
    const long orow = ((long)step * 128 + b) * 1024 + tid;
    vctxB[orow] = vc;
    lctxB[orow] = lc;
    kv = tanhf(kv + vc + lc);
    __syncthreads();  // protect q/wgt for next step
  }
  out_kvs[(long)b * 1024 + tid] = kv;
}

// ---------------------------------------------------------------------------
// batched lang LSTM (M=512 = 4 steps x 128): gates = gpB0+gpB1 + lbase[b]
// ---------------------------------------------------------------------------
__global__ __launch_bounds__(256) void lstm_batch(
    const float* __restrict__ gpB, const float* __restrict__ lbase,
    const float* __restrict__ sc1, float* __restrict__ hB,
    float* __restrict__ cB) {
  long idx = ((long)blockIdx.x * 256 + threadIdx.x) * 4;
  if (idx >= 512L * 1024) return;
  const int row = (int)(idx >> 10);   // step*128+b
  const int b = row & 127;
  const int d = (int)(idx & 1023);
  const long base = (long)row * 4096 + d;
  const long lbbase = (long)b * 4096 + d;
  f32x4 g[4];
#pragma unroll
  for (int gi = 0; gi < 4; ++gi) {
    const long o = gi * 1024;
    g[gi] = LD4(gpB + base + o) + LD4(gpB + SLB + base + o) +
            LD4(lbase + lbbase + o);
  }
  f32x4 cp = LD4(sc1 + (long)b * 1024 + d), cc, hh;
#pragma unroll
  for (int j = 0; j < 4; ++j) {
    float ccj = sigf(g[1][j]) * cp[j] + sigf(g[0][j]) * tanhf(g[2][j]);
    cc[j] = ccj;
    hh[j] = sigf(g[3][j]) * tanhf(ccj);
  }
  ST4(cB + idx, cc);
  ST4(hB + idx, hh);
}

// ---------------------------------------------------------------------------
// halt_scan: per-b halting recurrence over 4 steps; writes outA / new_h[1] /
// new_c[1] / cost into d_out and S = sum h_lang.
// ---------------------------------------------------------------------------
__global__ __launch_bounds__(256) void halt_scan(
    const float* __restrict__ gpc0, const float* __restrict__ gpc1,
    const float* __restrict__ cb1, const float* __restrict__ W2,
    const float* __restrict__ b2, const float* __restrict__ hB,
    const float* __restrict__ cB, const int* __restrict__ it,
    float* __restrict__ Sout, float* __restrict__ out) {
  const int b = blockIdx.x, tid = threadIdx.x;
  const int d0 = tid * 4;
  __shared__ float red[256];
  __shared__ float p_sh;
  const f32x4 w4 = LD4(W2 + d0);
  const f32x4 cb = LD4(cb1 + d0);
  f32x4 hl_acc = (f32x4){0.f, 0.f, 0.f, 0.f}, cl_acc = hl_acc, s_acc = hl_acc;
  float a = 0.f, sel = 1.f, cost = 0.f;

  for (int i = 0; i < 4; ++i) {
    const long o = ((long)i * 128 + b) * 1024 + d0;
    f32x4 rv = LD4(gpc0 + o) + LD4(gpc1 + o) + cb;
    float part = 0.f;
#pragma unroll
    for (int j = 0; j < 4; ++j) part += fmaxf(rv[j], 0.f) * w4[j];
    red[tid] = part;
    __syncthreads();
    for (int s = 128; s > 0; s >>= 1) {
      if (tid < s) red[tid] += red[tid + s];
      __syncthreads();
    }
    if (tid == 0) p_sh = sigf(red[0] + b2[0]);
    __syncthreads();
    const float p = p_sh;
    const float bs = p * (1.f - a) * sel;
    f32x4 hl = LD4(hB + o), cl = LD4(cB + o);
    hl_acc += hl * bs;
    cl_acc += cl * bs;
    s_acc += hl;                        // key update unmasked in reference
    cost += (float)(i + 1) * (1.f - p) * sel;
    a += bs;
    sel = (a < 1.f - EPS) ? sel : 0.f;
    __syncthreads();                    // p_sh reuse
  }
  const float inv_a = 1.f / a;
  const long ob = (long)b * 1024 + d0;
  ST4(out + ob, hl_acc * inv_a);             // outA
  ST4(out + O4 + BD + ob, hl_acc * inv_a);   // new_h[1]
  ST4(out + O5 + BD + ob, cl_acc * inv_a);   // new_c[1]
  ST4(Sout + ob, s_acc);
  if (tid == 0) out[O3 + b] = cost * ((it[b] > 0) ? 1.f : 0.f);
}

// ---------------------------------------------------------------------------
// finalize2: vkey/lkey outputs only (+0.01*S broadcast).
// ---------------------------------------------------------------------------
constexpr long VK = (long)B * NV * D;
constexpr long LK = (long)B * NL * D;

__global__ __launch_bounds__(256) void finalize2(
    const float* __restrict__ vkey0, const float* __restrict__ lkey0,
    const float* __restrict__ S, float* __restrict__ out) {
  long idx = ((long)blockIdx.x * 256 + threadIdx.x) * 4;
  if (idx < VK) {
    int b = (int)(idx / (NV * 1024));
    int d = (int)(idx & 1023);
    ST4(out + O1 + idx, LD4(vkey0 + idx) + LD4(S + (long)b * 1024 + d) * 0.01f);
  } else if (idx < VK + LK) {
    long r = idx - VK;
    int b = (int)(r / (NL * 1024));
    int d = (int)(r & 1023);
    ST4(out + O2 + r, LD4(lkey0 + r) + LD4(S + (long)b * 1024 + d) * 0.01f);
  }
}

// ---------------------------------------------------------------------------
extern "C" void kernel_launch(void* const* d_in, const int* in_sizes, int n_in,
                              void* d_out, int out_size, void* d_ws, size_t ws_size,
                              hipStream_t stream) {
  const float* xt   = (const float*)d_in[0];
  const int*   it   = (const int*)d_in[1];
  const float* fc   = (const float*)d_in[2];
  const float* vval = (const float*)d_in[3];
  const float* vkey = (const float*)d_in[4];
  const float* lval = (const float*)d_in[5];
  const float* lkey = (const float*)d_in[6];
  const float* kv0  = (const float*)d_in[7];
  const float* sh   = (const float*)d_in[8];   // [2,B,D]
  const float* sc   = (const float*)d_in[9];   // [2,B,D]
  // d_in[10] = max_att_step (4)
  const float* aWih = (const float*)d_in[11];  // [4096,3072]
  const float* aWhh = (const float*)d_in[12];  // [4096,1024]
  const float* abih = (const float*)d_in[13];
  const float* abhh = (const float*)d_in[14];
  const float* lWih = (const float*)d_in[15];  // [4096,3072]
  const float* lWhh = (const float*)d_in[16];  // [4096,1024]
  const float* lbih = (const float*)d_in[17];
  const float* lbhh = (const float*)d_in[18];
  const float* cW1  = (const float*)d_in[19];  // [1024,1024]
  const float* cb1  = (const float*)d_in[20];
  const float* cW2  = (const float*)d_in[21];  // [1,1024]
  const float* cb2  = (const float*)d_in[22];

  float* ws = (float*)d_ws;
  float* gpA   = ws + OFF_GPA;
  float* gpLB  = ws + OFF_GPLB;
  float* lbase = ws + OFF_LBASE;
  float* gpB   = ws + OFF_GPB;
  float* gpC0  = ws + OFF_GPC0;
  float* gpC1  = ws + OFF_GPC1;
  float* h_att = ws + OFF_HATT2;
  float* c_att = ws + OFF_CATT2;
  float* hB    = ws + OFF_HLB;
  float* cB    = ws + OFF_CLB;
  float* vctxB = ws + OFF_VCTXB;
  float* lctxB = ws + OFF_LCTXB;
  float* Sbuf  = ws + OFF_S2;
  __hip_bfloat16* vvb = (__hip_bfloat16*)(ws + OFF_VVB);
  __hip_bfloat16* lvb = (__hip_bfloat16*)(ws + OFF_LVB);
  __hip_bfloat16* vkb = (__hip_bfloat16*)(ws + OFF_VKB);
  __hip_bfloat16* lkb = (__hip_bfloat16*)(ws + OFF_LKB);

  const float* sh1 = sh + BD;  // state_h[1]
  const float* sc0 = sc;       // state_c[0]
  const float* sc1 = sc + BD;  // state_c[1]
  float* out = (float*)d_out;

  // 1) fused: att gates GEMM (z<8) + K/V bf16 prestage (z=8..11)
  {
    GemmArgs ga;
    ga.A[0] = sh1;       ga.W[0] = aWih;        ga.wstride[0] = 3072;
    ga.A[1] = sh1 + 512; ga.W[1] = aWih + 512;  ga.wstride[1] = 3072;
    ga.A[2] = fc;        ga.W[2] = aWih + 1024; ga.wstride[2] = 3072;
    ga.A[3] = fc + 512;  ga.W[3] = aWih + 1536; ga.wstride[3] = 3072;
    ga.A[4] = xt;        ga.W[4] = aWih + 2048; ga.wstride[4] = 3072;
    ga.A[5] = xt + 512;  ga.W[5] = aWih + 2560; ga.wstride[5] = 3072;
    ga.A[6] = sh;        ga.W[6] = aWhh;        ga.wstride[6] = 1024;
    ga.A[7] = sh + 512;  ga.W[7] = aWhh + 512;  ga.wstride[7] = 1024;
    ga.klen = 512;
    gemmA_prestage<<<dim3(64, 1, 12), 256, 0, stream>>>(
        ga, 4096, SL, gpA, vkey, lkey, vval, lval, vkb, lkb, vvb, lvb);
  }
  // 2) att LSTM -> h_att, c_att (+ new_h[0]/new_c[0] to out)
  lstm_att<<<128, 256, 0, stream>>>(gpA, abih, abhh, sc0, h_att, c_att, out);

  // 3) lbase partials: sh1@lWhh^T + h_att@lWih[:,2048:]^T (K quarters)
  {
    GemmArgs ga;
#pragma unroll
    for (int q = 0; q < 4; ++q) {
      ga.A[q] = sh1 + q * 256;
      ga.W[q] = lWhh + q * 256;
      ga.wstride[q] = 1024;
      ga.A[4 + q] = h_att + q * 256;
      ga.W[4 + q] = lWih + 2048 + q * 256;
      ga.wstride[4 + q] = 3072;
    }
    ga.klen = 256;
    gemm_mfma<<<dim3(64, 1, 8), 256, 0, stream>>>(ga, 4096, SL, gpLB);
  }
  // 4) lbase reduce (+ both biases)
  reduce8<<<512, 256, 0, stream>>>(gpLB, lbih, lbhh, lbase);

  // 5) all 4 attention steps (bf16 caches, ILP ctx)
  attn_mega<<<128, 1024, 0, stream>>>(h_att, kv0, vkb, lkb, vvb, lvb,
                                      vctxB, lctxB, out + O6);

  // 6) batched loop gates: M=512; lWih read 4x via L3.
  {
    GemmArgs ga;
    ga.A[0] = vctxB; ga.W[0] = lWih;        ga.wstride[0] = 3072;
    ga.A[1] = lctxB; ga.W[1] = lWih + 1024; ga.wstride[1] = 3072;
#pragma unroll
    for (int z = 2; z < 8; ++z) { ga.A[z] = vctxB; ga.W[z] = lWih; ga.wstride[z] = 3072; }
    ga.klen = 1024;
    gemm_mfma<<<dim3(64, 4, 2), 256, 0, stream>>>(ga, 4096, SLB, gpB);
  }
  // 7) batched lang LSTM
  lstm_batch<<<512, 256, 0, stream>>>(gpB, lbase, sc1, hB, cB);

  // 8) batched conf GEMM: M=512, N=1024, K=1024 split in 2
  {
    GemmArgs ga;
    ga.A[0] = hB;       ga.W[0] = cW1;       ga.wstride[0] = 1024;
    ga.A[1] = hB + 512; ga.W[1] = cW1 + 512; ga.wstride[1] = 1024;
#pragma unroll
    for (int z = 2; z < 8; ++z) { ga.A[z] = hB; ga.W[z] = cW1; ga.wstride[z] = 1024; }
    ga.klen = 512;
    gemm_mfma<<<dim3(16, 4, 2), 256, 0, stream>>>(ga, 1024, 524288, gpC0);
  }
  // 9) halting scan -> outA, new_h[1], new_c[1], cost, S
  halt_scan<<<128, 256, 0, stream>>>(gpC0, gpC1, cb1, cW2, cb2, hB, cB, it,
                                     Sbuf, out);
  // 10) key outputs
  finalize2<<<7168, 256, 0, stream>>>(vkey, lkey, Sbuf, out);
}

// Round 10
// 151.289 us; speedup vs baseline: 1.0615x; 1.0615x over previous
//
#include <hip/hip_runtime.h>
#include <hip/hip_bf16.h>

// Sizes (fixed by the reference setup)
constexpr int B  = 128;
constexpr int D  = 1024;
constexpr int NV = 36;
constexpr int NL = 20;
constexpr int BD = B * D;              // 131072
constexpr float EPS = 0.01f;
constexpr int NSLOT = 8;

// Workspace layout (floats)
constexpr long SL  = 524288;                     // [128][4096] slot
constexpr long SLB = 2097152;                    // [512][4096] slot
constexpr long OFF_GPA   = 0;                    // 8 slots (att gate partials)
constexpr long OFF_GPLB  = OFF_GPA + 8 * SL;     // 8 slots (lbase partials)
constexpr long OFF_LBASE = OFF_GPLB + 8 * SL;    // [128][4096] (incl. biases)
constexpr long OFF_GPB   = OFF_LBASE + SL;       // 2 slots [512][4096] (loop gates)
constexpr long OFF_GPC0  = OFF_GPB + 2 * SLB;    // conf slot 0 [512][1024]
constexpr long OFF_GPC1  = OFF_GPC0 + 524288;    // conf slot 1
constexpr long OFF_HATT2 = OFF_GPC1 + 524288;    // h_att [128][1024]
constexpr long OFF_CATT2 = OFF_HATT2 + BD;
constexpr long OFF_HLB   = OFF_CATT2 + BD;       // h_lang batched [512][1024]
constexpr long OFF_CLB   = OFF_HLB + 524288;
constexpr long OFF_VCTXB = OFF_CLB + 524288;     // vctx batched [512][1024]
constexpr long OFF_LCTXB = OFF_VCTXB + 524288;
constexpr long OFF_S2    = OFF_LCTXB + 524288;   // S = sum h_lang [128][1024]
constexpr long OFF_VVB   = OFF_S2 + BD;          // bf16 vval cache
constexpr long OFF_LVB   = OFF_VVB + 2359296;    // bf16 lval cache
constexpr long OFF_VKB   = OFF_LVB + 1310720;    // bf16 vkey cache
constexpr long OFF_LKB   = OFF_VKB + 2359296;    // bf16 lkey cache

typedef float f32x4 __attribute__((ext_vector_type(4)));
typedef short s16x8 __attribute__((ext_vector_type(8)));

__device__ __forceinline__ float sigf(float x) { return 1.f / (1.f + expf(-x)); }

__device__ __forceinline__ short f2bf(float f) {
  __hip_bfloat16 h = __float2bfloat16(f);
  return *reinterpret_cast<short*>(&h);
}
__device__ __forceinline__ float bf2f(short s) {
  unsigned u = ((unsigned)(unsigned short)s) << 16;
  return __uint_as_float(u);
}

__device__ __forceinline__ f32x4 LD4(const float* p) { return *(const f32x4*)p; }
__device__ __forceinline__ void ST4(float* p, f32x4 v) { *(f32x4*)p = v; }

// ---------------------------------------------------------------------------
// K/V f32 -> bf16 converter, full-machine streaming (2048 blocks).
// ---------------------------------------------------------------------------
__device__ __forceinline__ void conv_bf16(const float* __restrict__ src,
                                          __hip_bfloat16* __restrict__ dst,
                                          long nelem) {
  const long total = nelem >> 2;
  for (long i = (long)blockIdx.x * 256 + threadIdx.x; i < total;
       i += (long)gridDim.x * 256) {
    f32x4 v = LD4(src + i * 4);
    *(short4*)((short*)dst + i * 4) =
        short4{f2bf(v[0]), f2bf(v[1]), f2bf(v[2]), f2bf(v[3])};
  }
}

__global__ __launch_bounds__(256) void conv_kv(
    const float* __restrict__ vkey, const float* __restrict__ lkey,
    const float* __restrict__ vval, const float* __restrict__ lval,
    __hip_bfloat16* __restrict__ vkb, __hip_bfloat16* __restrict__ lkb,
    __hip_bfloat16* __restrict__ vvb, __hip_bfloat16* __restrict__ lvb) {
  conv_bf16(vkey, vkb, (long)B * NV * 1024);
  conv_bf16(lkey, lkb, (long)B * NL * 1024);
  conv_bf16(vval, vvb, (long)B * NV * 1024);
  conv_bf16(lval, lvb, (long)B * NL * 1024);
}

// ---------------------------------------------------------------------------
// MFMA bf16 GEMM: split-K partials, double-buffered LDS, tile BM=128 BN=64
// BK=64; blockIdx.(x,y,z) = (N-tile, M-tile, K-slot).
// ---------------------------------------------------------------------------
struct GemmArgs {
  const float* A[NSLOT];
  const float* W[NSLOT];
  long wstride[NSLOT];
  int klen;                // K per z (multiple of 64)
};

__global__ __launch_bounds__(256, 2) void gemm_mfma(GemmArgs ga, int N,
                                                    long pstride,
                                                    float* __restrict__ gpart) {
  __shared__ __align__(16) short As[2][128][72];
  __shared__ __align__(16) short Bs[2][64][72];
  const int z = blockIdx.z;
  const float* __restrict__ A = ga.A[z];
  const float* __restrict__ W = ga.W[z];
  const long wstr = ga.wstride[z];
  const int brow = blockIdx.y * 128;
  const int bcol = blockIdx.x * 64;
  float* __restrict__ out = gpart + (long)z * pstride;

  const int tid = threadIdx.x;
  const int wave = tid >> 6, lane = tid & 63;
  const int wr = wave >> 1, wc = wave & 1;
  const int lrow = lane & 15;
  const int lk8  = (lane >> 4) * 8;
  const int sr = tid >> 4;          // 0..15
  const int sc4 = (tid & 15) * 4;   // 0..60

  f32x4 acc[4][2];
#pragma unroll
  for (int m = 0; m < 4; ++m)
#pragma unroll
    for (int n = 0; n < 2; ++n) acc[m][n] = (f32x4){0.f, 0.f, 0.f, 0.f};

  float4 ra[8], rw[4];
#define LOAD_TILE(KT)                                                          \
  {                                                                            \
    const int kb = (KT) * 64;                                                  \
    _Pragma("unroll") for (int i = 0; i < 8; ++i) {                            \
      const int r = sr + i * 16;                                               \
      ra[i] = *(const float4*)(A + (long)(brow + r) * 1024 + kb + sc4);        \
    }                                                                          \
    _Pragma("unroll") for (int i = 0; i < 4; ++i) {                            \
      const int r = sr + i * 16;                                               \
      rw[i] = *(const float4*)(W + (long)(bcol + r) * wstr + kb + sc4);        \
    }                                                                          \
  }
#define WRITE_TILE(BUF)                                                        \
  {                                                                            \
    _Pragma("unroll") for (int i = 0; i < 8; ++i) {                            \
      const int r = sr + i * 16;                                               \
      *(short4*)(&As[BUF][r][sc4]) =                                           \
          short4{f2bf(ra[i].x), f2bf(ra[i].y), f2bf(ra[i].z), f2bf(ra[i].w)};  \
    }                                                                          \
    _Pragma("unroll") for (int i = 0; i < 4; ++i) {                            \
      const int r = sr + i * 16;                                               \
      *(short4*)(&Bs[BUF][r][sc4]) =                                           \
          short4{f2bf(rw[i].x), f2bf(rw[i].y), f2bf(rw[i].z), f2bf(rw[i].w)};  \
    }                                                                          \
  }

  const int ntiles = ga.klen / 64;
  LOAD_TILE(0);
  WRITE_TILE(0);
  __syncthreads();
  for (int kt = 0; kt < ntiles; ++kt) {
    const int cur = kt & 1;
    const bool more = (kt + 1 < ntiles);
    if (more) LOAD_TILE(kt + 1);  // in flight during MFMA phase
#pragma unroll
    for (int kk = 0; kk < 64; kk += 32) {
      s16x8 af[4], bf[2];
#pragma unroll
      for (int m = 0; m < 4; ++m)
        af[m] = *(const s16x8*)(&As[cur][wr * 64 + m * 16 + lrow][kk + lk8]);
#pragma unroll
      for (int n = 0; n < 2; ++n)
        bf[n] = *(const s16x8*)(&Bs[cur][wc * 32 + n * 16 + lrow][kk + lk8]);
#pragma unroll
      for (int m = 0; m < 4; ++m)
#pragma unroll
        for (int n = 0; n < 2; ++n)
          acc[m][n] = __builtin_amdgcn_mfma_f32_16x16x32_bf16(
              af[m], bf[n], acc[m][n], 0, 0, 0);
    }
    if (more) WRITE_TILE(1 - cur);
    __syncthreads();
  }
#undef LOAD_TILE
#undef WRITE_TILE

  // C/D layout: col=lane&15, row=(lane>>4)*4+reg
#pragma unroll
  for (int m = 0; m < 4; ++m) {
#pragma unroll
    for (int n = 0; n < 2; ++n) {
      const int col = bcol + wc * 32 + n * 16 + lrow;
#pragma unroll
      for (int r = 0; r < 4; ++r) {
        const int row = brow + wr * 64 + m * 16 + (lane >> 4) * 4 + r;
        out[(long)row * N + col] = acc[m][n][r];
      }
    }
  }
}

// ---------------------------------------------------------------------------
// att LSTM cell: gates = sum of 8 partials + bih + bhh -> h_att, c_att.
// Also writes new_h[0] / new_c[0] sections of d_out directly.
// ---------------------------------------------------------------------------
constexpr long O1 = BD;
constexpr long O2 = O1 + (long)B * NV * D;
constexpr long O3 = O2 + (long)B * NL * D;
constexpr long O4 = O3 + B;
constexpr long O5 = O4 + 2L * BD;
constexpr long O6 = O5 + 2L * BD;
constexpr long O7 = O6 + BD;

__global__ __launch_bounds__(256) void lstm_att(
    const float* __restrict__ gp, const float* __restrict__ bih,
    const float* __restrict__ bhh, const float* __restrict__ c_prev,
    float* __restrict__ h, float* __restrict__ c, float* __restrict__ out) {
  long idx = ((long)blockIdx.x * 256 + threadIdx.x) * 4;
  if (idx >= BD) return;
  int b = (int)(idx >> 10), d = (int)(idx & 1023);
  const long base = (long)b * 4096 + d;
  f32x4 g[4];
#pragma unroll
  for (int gi = 0; gi < 4; ++gi) {
    const long o = base + gi * 1024;
    f32x4 v = LD4(bih + gi * 1024 + d) + LD4(bhh + gi * 1024 + d);
#pragma unroll
    for (int s = 0; s < NSLOT; ++s) v += LD4(gp + s * SL + o);
    g[gi] = v;
  }
  f32x4 cp = LD4(c_prev + idx), cc, hh;
#pragma unroll
  for (int j = 0; j < 4; ++j) {
    float ccj = sigf(g[1][j]) * cp[j] + sigf(g[0][j]) * tanhf(g[2][j]);
    cc[j] = ccj;
    hh[j] = sigf(g[3][j]) * tanhf(ccj);
  }
  ST4(c + idx, cc);
  ST4(h + idx, hh);
  ST4(out + O4 + idx, hh);   // new_h[0] == hA/accum == h_att
  ST4(out + O5 + idx, cc);   // new_c[0] == cA/accum == c_att
}

// ---------------------------------------------------------------------------
// reduce8: lbase = sum of 8 partials + bih + bhh
// ---------------------------------------------------------------------------
__global__ __launch_bounds__(256) void reduce8(
    const float* __restrict__ gp, const float* __restrict__ bih,
    const float* __restrict__ bhh, float* __restrict__ out) {
  long idx = ((long)blockIdx.x * 256 + threadIdx.x) * 4;
  if (idx >= (long)B * 4096) return;
  int col = (int)(idx & 4095);
  f32x4 v = LD4(bih + col) + LD4(bhh + col);
#pragma unroll
  for (int s = 0; s < NSLOT; ++s) v += LD4(gp + s * SL + idx);
  ST4(out + idx, v);
}

// ---------------------------------------------------------------------------
// attn_mega v3: all 4 attention steps per batch element, 1024 threads.
// Keys staged into LDS from the bf16 cache (L3-warm, half bytes). Values
// read bf16 all steps with 4-way accumulator ILP. kvs recurrence in
// registers. Softmax over ORIGINAL keys (slot-uniform update cancels).
// ---------------------------------------------------------------------------
__global__ __launch_bounds__(1024) void attn_mega(
    const float* __restrict__ h_att, const float* __restrict__ kv0,
    const __hip_bfloat16* __restrict__ vkb, const __hip_bfloat16* __restrict__ lkb,
    const __hip_bfloat16* __restrict__ vvb, const __hip_bfloat16* __restrict__ lvb,
    float* __restrict__ vctxB, float* __restrict__ lctxB,
    float* __restrict__ out_kvs) {
  const int b = blockIdx.x, tid = threadIdx.x;   // tid = d column
  __shared__ short K[56][1024];                  // 112 KB bf16 keys
  __shared__ float q[1024];
  __shared__ float wgt[64];
  const int wave = tid >> 6, lane = tid & 63;

  // stage all 56 keys from bf16 cache (s16x8 = 16B per thread-iter)
  for (int i = tid; i < 56 * 128; i += 1024) {
    const int r = i >> 7, c8 = (i & 127) * 8;
    const __hip_bfloat16* kp = (r < NV)
        ? vkb + ((long)b * NV + r) * 1024
        : lkb + ((long)b * NL + (r - NV)) * 1024;
    *(s16x8*)(&K[r][c8]) = *(const s16x8*)(kp + c8);
  }

  const float ha = h_att[(long)b * 1024 + tid];
  float kv = kv0[(long)b * 1024 + tid];

  for (int step = 0; step < 4; ++step) {
    q[tid] = ha + kv;
    __syncthreads();   // orders K staging (iter 0) and q writes before reads
    // logits: 56 keys over 16 waves, pure LDS
    for (int n = wave; n < NV + NL; n += 16) {
      float s = 0.f;
#pragma unroll
      for (int j = 0; j < 2; ++j) {
        const int base = lane * 8 + j * 512;
        s16x8 k8 = *(const s16x8*)(&K[n][base]);
        f32x4 q0 = *(const f32x4*)(&q[base]);
        f32x4 q1 = *(const f32x4*)(&q[base + 4]);
#pragma unroll
        for (int e = 0; e < 4; ++e) {
          s += bf2f(k8[e]) * q0[e];
          s += bf2f(k8[e + 4]) * q1[e];
        }
      }
      for (int m = 32; m >= 1; m >>= 1) s += __shfl_xor(s, m);
      if (lane == 0) wgt[n] = s * (1.0f / 32.0f);
    }
    __syncthreads();
    // softmax (wave0: visual, wave1: language)
    if (wave == 0) {
      float x = (lane < NV) ? wgt[lane] : -1e30f;
      float m = x;
      for (int k = 32; k >= 1; k >>= 1) m = fmaxf(m, __shfl_xor(m, k));
      float e = (lane < NV) ? expf(x - m) : 0.f;
      float ssum = e;
      for (int k = 32; k >= 1; k >>= 1) ssum += __shfl_xor(ssum, k);
      if (lane < NV) wgt[lane] = e / ssum;
    } else if (wave == 1) {
      float x = (lane < NL) ? wgt[NV + lane] : -1e30f;
      float m = x;
      for (int k = 32; k >= 1; k >>= 1) m = fmaxf(m, __shfl_xor(m, k));
      float e = (lane < NL) ? expf(x - m) : 0.f;
      float ssum = e;
      for (int k = 32; k >= 1; k >>= 1) ssum += __shfl_xor(ssum, k);
      if (lane < NL) wgt[NV + lane] = e / ssum;
    }
    __syncthreads();
    // context + kvs update: 1 col/thread, bf16, 4-way accumulator ILP
    const __hip_bfloat16* vb = vvb + (long)b * NV * 1024 + tid;
    float a0 = 0.f, a1 = 0.f, a2 = 0.f, a3 = 0.f;
#pragma unroll
    for (int n = 0; n < NV; n += 4) {
      a0 += __bfloat162float(vb[(long)(n + 0) * 1024]) * wgt[n + 0];
      a1 += __bfloat162float(vb[(long)(n + 1) * 1024]) * wgt[n + 1];
      a2 += __bfloat162float(vb[(long)(n + 2) * 1024]) * wgt[n + 2];
      a3 += __bfloat162float(vb[(long)(n + 3) * 1024]) * wgt[n + 3];
    }
    const float vc = (a0 + a1) + (a2 + a3);
    const __hip_bfloat16* lb = lvb + (long)b * NL * 1024 + tid;
    float c0 = 0.f, c1 = 0.f, c2 = 0.f, c3 = 0.f;
#pragma unroll
    for (int n = 0; n < NL; n += 4) {
      c0 += __bfloat162float(lb[(long)(n + 0) * 1024]) * wgt[NV + n + 0];
      c1 += __bfloat162float(lb[(long)(n + 1) * 1024]) * wgt[NV + n + 1];
      c2 += __bfloat162float(lb[(long)(n + 2) * 1024]) * wgt[NV + n + 2];
      c3 += __bfloat162float(lb[(long)(n + 3) * 1024]) * wgt[NV + n + 3];
    }
    const float lc = (c0 + c1) + (c2 + c3);
    const long orow = ((long)step * 128 + b) * 1024 + tid;
    vctxB[orow] = vc;
    lctxB[orow] = lc;
    kv = tanhf(kv + vc + lc);
    __syncthreads();  // protect q/wgt for next step
  }
  out_kvs[(long)b * 1024 + tid] = kv;
}

// ---------------------------------------------------------------------------
// batched lang LSTM (M=512 = 4 steps x 128): gates = gpB0+gpB1 + lbase[b]
// ---------------------------------------------------------------------------
__global__ __launch_bounds__(256) void lstm_batch(
    const float* __restrict__ gpB, const float* __restrict__ lbase,
    const float* __restrict__ sc1, float* __restrict__ hB,
    float* __restrict__ cB) {
  long idx = ((long)blockIdx.x * 256 + threadIdx.x) * 4;
  if (idx >= 512L * 1024) return;
  const int row = (int)(idx >> 10);   // step*128+b
  const int b = row & 127;
  const int d = (int)(idx & 1023);
  const long base = (long)row * 4096 + d;
  const long lbbase = (long)b * 4096 + d;
  f32x4 g[4];
#pragma unroll
  for (int gi = 0; gi < 4; ++gi) {
    const long o = gi * 1024;
    g[gi] = LD4(gpB + base + o) + LD4(gpB + SLB + base + o) +
            LD4(lbase + lbbase + o);
  }
  f32x4 cp = LD4(sc1 + (long)b * 1024 + d), cc, hh;
#pragma unroll
  for (int j = 0; j < 4; ++j) {
    float ccj = sigf(g[1][j]) * cp[j] + sigf(g[0][j]) * tanhf(g[2][j]);
    cc[j] = ccj;
    hh[j] = sigf(g[3][j]) * tanhf(ccj);
  }
  ST4(cB + idx, cc);
  ST4(hB + idx, hh);
}

// ---------------------------------------------------------------------------
// halt_scan: per-b halting recurrence over 4 steps; writes outA / new_h[1] /
// new_c[1] / cost into d_out and S = sum h_lang.
// ---------------------------------------------------------------------------
__global__ __launch_bounds__(256) void halt_scan(
    const float* __restrict__ gpc0, const float* __restrict__ gpc1,
    const float* __restrict__ cb1, const float* __restrict__ W2,
    const float* __restrict__ b2, const float* __restrict__ hB,
    const float* __restrict__ cB, const int* __restrict__ it,
    float* __restrict__ Sout, float* __restrict__ out) {
  const int b = blockIdx.x, tid = threadIdx.x;
  const int d0 = tid * 4;
  __shared__ float red[256];
  __shared__ float p_sh;
  const f32x4 w4 = LD4(W2 + d0);
  const f32x4 cb = LD4(cb1 + d0);
  f32x4 hl_acc = (f32x4){0.f, 0.f, 0.f, 0.f}, cl_acc = hl_acc, s_acc = hl_acc;
  float a = 0.f, sel = 1.f, cost = 0.f;

  for (int i = 0; i < 4; ++i) {
    const long o = ((long)i * 128 + b) * 1024 + d0;
    f32x4 rv = LD4(gpc0 + o) + LD4(gpc1 + o) + cb;
    float part = 0.f;
#pragma unroll
    for (int j = 0; j < 4; ++j) part += fmaxf(rv[j], 0.f) * w4[j];
    red[tid] = part;
    __syncthreads();
    for (int s = 128; s > 0; s >>= 1) {
      if (tid < s) red[tid] += red[tid + s];
      __syncthreads();
    }
    if (tid == 0) p_sh = sigf(red[0] + b2[0]);
    __syncthreads();
    const float p = p_sh;
    const float bs = p * (1.f - a) * sel;
    f32x4 hl = LD4(hB + o), cl = LD4(cB + o);
    hl_acc += hl * bs;
    cl_acc += cl * bs;
    s_acc += hl;                        // key update unmasked in reference
    cost += (float)(i + 1) * (1.f - p) * sel;
    a += bs;
    sel = (a < 1.f - EPS) ? sel : 0.f;
    __syncthreads();                    // p_sh reuse
  }
  const float inv_a = 1.f / a;
  const long ob = (long)b * 1024 + d0;
  ST4(out + ob, hl_acc * inv_a);             // outA
  ST4(out + O4 + BD + ob, hl_acc * inv_a);   // new_h[1]
  ST4(out + O5 + BD + ob, cl_acc * inv_a);   // new_c[1]
  ST4(Sout + ob, s_acc);
  if (tid == 0) out[O3 + b] = cost * ((it[b] > 0) ? 1.f : 0.f);
}

// ---------------------------------------------------------------------------
// finalize2: vkey/lkey outputs only (+0.01*S broadcast).
// ---------------------------------------------------------------------------
constexpr long VK = (long)B * NV * D;
constexpr long LK = (long)B * NL * D;

__global__ __launch_bounds__(256) void finalize2(
    const float* __restrict__ vkey0, const float* __restrict__ lkey0,
    const float* __restrict__ S, float* __restrict__ out) {
  long idx = ((long)blockIdx.x * 256 + threadIdx.x) * 4;
  if (idx < VK) {
    int b = (int)(idx / (NV * 1024));
    int d = (int)(idx & 1023);
    ST4(out + O1 + idx, LD4(vkey0 + idx) + LD4(S + (long)b * 1024 + d) * 0.01f);
  } else if (idx < VK + LK) {
    long r = idx - VK;
    int b = (int)(r / (NL * 1024));
    int d = (int)(r & 1023);
    ST4(out + O2 + r, LD4(lkey0 + r) + LD4(S + (long)b * 1024 + d) * 0.01f);
  }
}

// ---------------------------------------------------------------------------
extern "C" void kernel_launch(void* const* d_in, const int* in_sizes, int n_in,
                              void* d_out, int out_size, void* d_ws, size_t ws_size,
                              hipStream_t stream) {
  const float* xt   = (const float*)d_in[0];
  const int*   it   = (const int*)d_in[1];
  const float* fc   = (const float*)d_in[2];
  const float* vval = (const float*)d_in[3];
  const float* vkey = (const float*)d_in[4];
  const float* lval = (const float*)d_in[5];
  const float* lkey = (const float*)d_in[6];
  const float* kv0  = (const float*)d_in[7];
  const float* sh   = (const float*)d_in[8];   // [2,B,D]
  const float* sc   = (const float*)d_in[9];   // [2,B,D]
  // d_in[10] = max_att_step (4)
  const float* aWih = (const float*)d_in[11];  // [4096,3072]
  const float* aWhh = (const float*)d_in[12];  // [4096,1024]
  const float* abih = (const float*)d_in[13];
  const float* abhh = (const float*)d_in[14];
  const float* lWih = (const float*)d_in[15];  // [4096,3072]
  const float* lWhh = (const float*)d_in[16];  // [4096,1024]
  const float* lbih = (const float*)d_in[17];
  const float* lbhh = (const float*)d_in[18];
  const float* cW1  = (const float*)d_in[19];  // [1024,1024]
  const float* cb1  = (const float*)d_in[20];
  const float* cW2  = (const float*)d_in[21];  // [1,1024]
  const float* cb2  = (const float*)d_in[22];

  float* ws = (float*)d_ws;
  float* gpA   = ws + OFF_GPA;
  float* gpLB  = ws + OFF_GPLB;
  float* lbase = ws + OFF_LBASE;
  float* gpB   = ws + OFF_GPB;
  float* gpC0  = ws + OFF_GPC0;
  float* gpC1  = ws + OFF_GPC1;
  float* h_att = ws + OFF_HATT2;
  float* c_att = ws + OFF_CATT2;
  float* hB    = ws + OFF_HLB;
  float* cB    = ws + OFF_CLB;
  float* vctxB = ws + OFF_VCTXB;
  float* lctxB = ws + OFF_LCTXB;
  float* Sbuf  = ws + OFF_S2;
  __hip_bfloat16* vvb = (__hip_bfloat16*)(ws + OFF_VVB);
  __hip_bfloat16* lvb = (__hip_bfloat16*)(ws + OFF_LVB);
  __hip_bfloat16* vkb = (__hip_bfloat16*)(ws + OFF_VKB);
  __hip_bfloat16* lkb = (__hip_bfloat16*)(ws + OFF_LKB);

  const float* sh1 = sh + BD;  // state_h[1]
  const float* sc0 = sc;       // state_c[0]
  const float* sc1 = sc + BD;  // state_c[1]
  float* out = (float*)d_out;

  // 0) K/V f32 -> bf16 caches, full-machine streaming
  conv_kv<<<2048, 256, 0, stream>>>(vkey, lkey, vval, lval, vkb, lkb, vvb, lvb);

  // 1) att gates: [sh1,fc,xt]@aWih^T + sh0@aWhh^T, K pairs split in 2
  {
    GemmArgs ga;
    ga.A[0] = sh1;       ga.W[0] = aWih;        ga.wstride[0] = 3072;
    ga.A[1] = sh1 + 512; ga.W[1] = aWih + 512;  ga.wstride[1] = 3072;
    ga.A[2] = fc;        ga.W[2] = aWih + 1024; ga.wstride[2] = 3072;
    ga.A[3] = fc + 512;  ga.W[3] = aWih + 1536; ga.wstride[3] = 3072;
    ga.A[4] = xt;        ga.W[4] = aWih + 2048; ga.wstride[4] = 3072;
    ga.A[5] = xt + 512;  ga.W[5] = aWih + 2560; ga.wstride[5] = 3072;
    ga.A[6] = sh;        ga.W[6] = aWhh;        ga.wstride[6] = 1024;
    ga.A[7] = sh + 512;  ga.W[7] = aWhh + 512;  ga.wstride[7] = 1024;
    ga.klen = 512;
    gemm_mfma<<<dim3(64, 1, 8), 256, 0, stream>>>(ga, 4096, SL, gpA);
  }
  // 2) att LSTM -> h_att, c_att (+ new_h[0]/new_c[0] to out)
  lstm_att<<<128, 256, 0, stream>>>(gpA, abih, abhh, sc0, h_att, c_att, out);

  // 3) lbase partials: sh1@lWhh^T + h_att@lWih[:,2048:]^T (K quarters)
  {
    GemmArgs ga;
#pragma unroll
    for (int q = 0; q < 4; ++q) {
      ga.A[q] = sh1 + q * 256;
      ga.W[q] = lWhh + q * 256;
      ga.wstride[q] = 1024;
      ga.A[4 + q] = h_att + q * 256;
      ga.W[4 + q] = lWih + 2048 + q * 256;
      ga.wstride[4 + q] = 3072;
    }
    ga.klen = 256;
    gemm_mfma<<<dim3(64, 1, 8), 256, 0, stream>>>(ga, 4096, SL, gpLB);
  }
  // 4) lbase reduce (+ both biases)
  reduce8<<<512, 256, 0, stream>>>(gpLB, lbih, lbhh, lbase);

  // 5) all 4 attention steps (bf16 caches, ILP ctx)
  attn_mega<<<128, 1024, 0, stream>>>(h_att, kv0, vkb, lkb, vvb, lvb,
                                      vctxB, lctxB, out + O6);

  // 6) batched loop gates: M=512; lWih read 4x via L3.
  {
    GemmArgs ga;
    ga.A[0] = vctxB; ga.W[0] = lWih;        ga.wstride[0] = 3072;
    ga.A[1] = lctxB; ga.W[1] = lWih + 1024; ga.wstride[1] = 3072;
#pragma unroll
    for (int z = 2; z < 8; ++z) { ga.A[z] = vctxB; ga.W[z] = lWih; ga.wstride[z] = 3072; }
    ga.klen = 1024;
    gemm_mfma<<<dim3(64, 4, 2), 256, 0, stream>>>(ga, 4096, SLB, gpB);
  }
  // 7) batched lang LSTM
  lstm_batch<<<512, 256, 0, stream>>>(gpB, lbase, sc1, hB, cB);

  // 8) batched conf GEMM: M=512, N=1024, K=1024 split in 2
  {
    GemmArgs ga;
    ga.A[0] = hB;       ga.W[0] = cW1;       ga.wstride[0] = 1024;
    ga.A[1] = hB + 512; ga.W[1] = cW1 + 512; ga.wstride[1] = 1024;
#pragma unroll
    for (int z = 2; z < 8; ++z) { ga.A[z] = hB; ga.W[z] = cW1; ga.wstride[z] = 1024; }
    ga.klen = 512;
    gemm_mfma<<<dim3(16, 4, 2), 256, 0, stream>>>(ga, 1024, 524288, gpC0);
  }
  // 9) halting scan -> outA, new_h[1], new_c[1], cost, S
  halt_scan<<<128, 256, 0, stream>>>(gpC0, gpC1, cb1, cW2, cb2, hB, cB, it,
                                     Sbuf, out);
  // 10) key outputs
  finalize2<<<7168, 256, 0, stream>>>(vkey, lkey, Sbuf, out);
}